// Round 6
// baseline (261.329 us; speedup 1.0000x reference)
//
#include <hip/hip_runtime.h>
#include <stdint.h>

// MHA forward.  Inputs FP32, OUTPUT FP32 (reference computes in jnp.float32;
// rounds 4/5 cross-validated: bf16-out misread as fp32 gave the 1.12 signature).
// Compute: bf16 MFMA, fp32 accumulate.  B=2,S=2048,D=1024,H=16,HD=64.
//
// HEAD-SLICED pipeline (hs = heads per slice, chosen from ws_size on host):
//   per slice [h0, h0+hs):
//     t1 transpose_cols : fp32 Wq/Wk/Wv cols -> bf16 WT3sl[3*hs*64][1024]
//     k2 gemm_bt<3,1>   : fp32 x @ WT3sl^T -> Qsl/Ksl [b][s][hs*64], VTsl [b*hs+hh][64][s]
//     k3 attn_fwd       : flash attention -> A2sl [(b*hs+hh)][2048][64] bf16
//     k4 gemm_bt<1,0>   : A2sl(viewed [2*hs*128][1024]) @ WoT^T + bo -> FP32 out rows
//                         {b*2048 + (h0+hh)*128 + a}   (reference's no-transpose reshape)
//   WoT transposed once. Scratch = 2MB + hs*2.375MB (hs=2 -> 6.75MB; ws>=8MB proven r5).

typedef unsigned short u16;
typedef __attribute__((ext_vector_type(8))) short bf16x8;
typedef __attribute__((ext_vector_type(4))) float f32x4;

#define MFMA_BF16(a, b, c) __builtin_amdgcn_mfma_f32_16x16x32_bf16((a), (b), (c), 0, 0, 0)

__device__ __forceinline__ u16 f2bf(float f) {  // RNE
  union { float f; unsigned int u; } x; x.f = f;
  unsigned int r = x.u + 0x7fffu + ((x.u >> 16) & 1u);
  return (u16)(r >> 16);
}
// NaN -> -lim, +-inf -> +-lim, identity on real data (lim >> real range)
__device__ __forceinline__ float sat(float v, float lim) {
  return fminf(fmaxf(v, -lim), lim);
}
__device__ __forceinline__ bf16x8 pack8(float4 a, float4 b) {
  bf16x8 r;
  r[0] = (short)f2bf(a.x); r[1] = (short)f2bf(a.y);
  r[2] = (short)f2bf(a.z); r[3] = (short)f2bf(a.w);
  r[4] = (short)f2bf(b.x); r[5] = (short)f2bf(b.y);
  r[6] = (short)f2bf(b.z); r[7] = (short)f2bf(b.w);
  return r;
}

// XOR-swizzled 16B-chunk offset (in u16 elems). CPR = 16B chunks per row (pow2).
template <int CPR>
__device__ __forceinline__ int sw_off(int r, int c) {
  return (r * CPR + (c ^ (r & (CPR - 1)))) * 8;
}

// ---- t1: T[j][k] = bf16( Wg[k][h0*64 + (j - g*hsx64)] ),  W* are FP32 ----
__global__ void transpose_cols(const float* __restrict__ W0, const float* __restrict__ W1,
                               const float* __restrict__ W2, u16* __restrict__ T,
                               int h0, int hsx64) {
  __shared__ u16 t[32][33];
  const int j0 = blockIdx.x * 32;  // hsx64 multiple of 32 -> no W straddle
  const int g = j0 / hsx64;
  const float* W = (g == 0) ? W0 : (g == 1) ? W1 : W2;
  const int wc0 = h0 * 64 + (j0 % hsx64);
  const int k0 = blockIdx.y * 32;
  t[threadIdx.y][threadIdx.x] =
      f2bf(W[(size_t)(k0 + threadIdx.y) * 1024 + wc0 + threadIdx.x]);
  __syncthreads();
  T[(size_t)(j0 + threadIdx.y) * 1024 + k0 + threadIdx.x] = t[threadIdx.x][threadIdx.y];
}

// ---- k2/k4: C = A[M][K] @ BT[N][K]^T, 128x128 tile, 16x16x32 bf16 MFMA ----
// AF32: A is fp32 (converted during staging); else A is bf16.
// MODE 3 (QKV slice): n<hs64 -> Qsl, n<2*hs64 -> Ksl, else VTsl (all bf16).
// MODE 1 (out): +bias(fp32), FP32 store, row remap (b,rp) -> b*2048 + h0*128 + rp.
template <int MODE, int AF32>
__global__ __launch_bounds__(256, 2) void gemm_bt(
    const void* __restrict__ Av, const u16* __restrict__ BT,
    void* __restrict__ C0v, u16* __restrict__ C1, u16* __restrict__ C2,
    const float* __restrict__ bias, int M, int N, int K, int hs, int h0) {
  __shared__ __align__(16) u16 lsA[128 * 32];  // 8KB, CPR=4 swizzled
  __shared__ __align__(16) u16 lsB[128 * 32];
  const int tid = threadIdx.x, lane = tid & 63, wv = tid >> 6;
  const int quad = lane >> 4, l16 = lane & 15;
  const int m0 = blockIdx.y * 128, n0 = blockIdx.x * 128;
  const int wm = (wv >> 1) * 64, wn = (wv & 1) * 64;
  const int hs64 = hs * 64;
  f32x4 acc[4][4] = {};

  for (int k0 = 0; k0 < K; k0 += 32) {
    bf16x8 va[2], vb[2];
#pragma unroll
    for (int c = 0; c < 2; ++c) {
      const int P = c * 256 + tid, r = P >> 2, cc = P & 3;
      if constexpr (AF32) {
        const float* Af = (const float*)Av;
        const float4 a0 = *(const float4*)&Af[(size_t)(m0 + r) * K + k0 + cc * 8];
        const float4 a1 = *(const float4*)&Af[(size_t)(m0 + r) * K + k0 + cc * 8 + 4];
        va[c] = pack8(a0, a1);
      } else {
        va[c] = *(const bf16x8*)&((const u16*)Av)[(size_t)(m0 + r) * K + k0 + cc * 8];
      }
      vb[c] = *(const bf16x8*)&BT[(size_t)(n0 + r) * K + k0 + cc * 8];
    }
    __syncthreads();  // previous iteration's LDS reads complete
#pragma unroll
    for (int c = 0; c < 2; ++c) {
      const int P = c * 256 + tid, r = P >> 2, cc = P & 3;
      *(bf16x8*)&lsA[sw_off<4>(r, cc)] = va[c];
      *(bf16x8*)&lsB[sw_off<4>(r, cc)] = vb[c];
    }
    __syncthreads();
    bf16x8 af[4], bfr[4];
#pragma unroll
    for (int i = 0; i < 4; ++i) af[i] = *(const bf16x8*)&lsA[sw_off<4>(wm + i * 16 + l16, quad)];
#pragma unroll
    for (int j = 0; j < 4; ++j) bfr[j] = *(const bf16x8*)&lsB[sw_off<4>(wn + j * 16 + l16, quad)];
#pragma unroll
    for (int i = 0; i < 4; ++i)
#pragma unroll
      for (int j = 0; j < 4; ++j) acc[i][j] = MFMA_BF16(af[i], bfr[j], acc[i][j]);
  }

  // D layout: col = l16, row = quad*4 + r  (m89-verified)
#pragma unroll
  for (int i = 0; i < 4; ++i)
#pragma unroll
    for (int j = 0; j < 4; ++j) {
      const int n = n0 + wn + j * 16 + l16;
      float bv = 0.f;
      if constexpr (MODE == 1) bv = bias[n];
#pragma unroll
      for (int r = 0; r < 4; ++r) {
        const int m = m0 + wm + i * 16 + quad * 4 + r;
        if constexpr (MODE == 3) {
          const float v = sat(acc[i][j][r], 448.f);
          const int b = m >> 11, s = m & 2047;
          if (n < hs64) {
            ((u16*)C0v)[((size_t)b * 2048 + s) * hs64 + n] = f2bf(v);
          } else if (n < 2 * hs64) {
            C1[((size_t)b * 2048 + s) * hs64 + (n - hs64)] = f2bf(v);
          } else {
            const int nn = n - 2 * hs64;
            C2[((size_t)(b * hs + (nn >> 6)) * 64 + (nn & 63)) * 2048 + s] = f2bf(v);
          }
        } else {
          const float v = sat(acc[i][j][r] + bv, 1024.f);
          const int b = (m >= hs * 128) ? 1 : 0;
          const int rp = m - b * hs * 128;
          ((float*)C0v)[(size_t)(b * 2048 + h0 * 128 + rp) * 1024 + n] = v;  // FP32 out
        }
      }
    }
}

// ---- k3: causal flash attention for one head-slice (bf16 in/out, fp32 softmax) ----
// Grid (16, 2*hs): x -> q-tile (reversed, heavy first), y -> b*hs + hh.
__global__ __launch_bounds__(256, 2) void attn_fwd(
    const u16* __restrict__ Qsl, const u16* __restrict__ Ksl,
    const u16* __restrict__ VTsl, u16* __restrict__ A2sl, int hs) {
  __shared__ __align__(16) u16 lsK[128 * 64];    // 16KB [key][hd], CPR=8
  __shared__ __align__(16) u16 lsV[64 * 128];    // 16KB [hd][key], CPR=16
  __shared__ __align__(16) u16 lsP[4][32 * 48];  // per-wave P bounce
  const int tid = threadIdx.x, lane = tid & 63, wv = tid >> 6;
  const int quad = lane >> 4, l16 = lane & 15;
  const int qt = (int)gridDim.x - 1 - (int)blockIdx.x;
  const int bh = blockIdx.y;
  const int b = (bh >= hs) ? 1 : 0, hh = bh - b * hs;
  const int hs64 = hs * 64;
  const int q0 = qt * 128, wm = wv * 32;
  const u16* Qb = Qsl + (size_t)b * 2048 * hs64;             // [2048][hs64]
  const u16* Kb = Ksl + (size_t)b * 2048 * hs64;             // [2048][hs64]
  const u16* Vb = VTsl + (size_t)(b * hs + hh) * 64 * 2048;  // [64][2048]
  u16* A2b = A2sl + (size_t)(b * hs + hh) * 2048 * 64;       // [2048][64]
  u16* lsPw = &lsP[wv][0];

  bf16x8 qf[2][2];
#pragma unroll
  for (int mi = 0; mi < 2; ++mi)
#pragma unroll
    for (int ks = 0; ks < 2; ++ks)
      qf[mi][ks] = *(const bf16x8*)&Qb[(size_t)(q0 + wm + mi * 16 + l16) * hs64 +
                                       hh * 64 + ks * 32 + quad * 8];

  float m_run[2][4], l_run[2][4];
  f32x4 acc_o[2][4] = {};
#pragma unroll
  for (int mi = 0; mi < 2; ++mi)
#pragma unroll
    for (int r = 0; r < 4; ++r) { m_run[mi][r] = -INFINITY; l_run[mi][r] = 0.f; }

  for (int kt = 0; kt <= qt; ++kt) {
    const int k0 = kt * 128;
    bf16x8 vk[4], vv[4];
#pragma unroll
    for (int c = 0; c < 4; ++c) {
      const int P = c * 256 + tid;
      vk[c] = *(const bf16x8*)&Kb[(size_t)(k0 + (P >> 3)) * hs64 + hh * 64 + (P & 7) * 8];
      vv[c] = *(const bf16x8*)&Vb[(size_t)(P >> 4) * 2048 + k0 + (P & 15) * 8];
    }
    __syncthreads();  // previous iteration's LDS reads complete
#pragma unroll
    for (int c = 0; c < 4; ++c) {
      const int P = c * 256 + tid;
      *(bf16x8*)&lsK[sw_off<8>(P >> 3, P & 7)] = vk[c];
      *(bf16x8*)&lsV[sw_off<16>(P >> 4, P & 15)] = vv[c];
    }
    __syncthreads();

    // S = Q K^T
    f32x4 accs[2][8] = {};
#pragma unroll
    for (int ks = 0; ks < 2; ++ks) {
      bf16x8 kf[8];
#pragma unroll
      for (int nj = 0; nj < 8; ++nj)
        kf[nj] = *(const bf16x8*)&lsK[sw_off<8>(nj * 16 + l16, ks * 4 + quad)];
#pragma unroll
      for (int mi = 0; mi < 2; ++mi)
#pragma unroll
        for (int nj = 0; nj < 8; ++nj)
          accs[mi][nj] = MFMA_BF16(qf[mi][ks], kf[nj], accs[mi][nj]);
    }

    // online softmax (scale=1/8, causal mask like the reference)
#pragma unroll
    for (int mi = 0; mi < 2; ++mi) {
#pragma unroll
      for (int r = 0; r < 4; ++r) {
        const int grow = q0 + wm + mi * 16 + quad * 4 + r;
        float vals[8], mx = -1.0e6f;
#pragma unroll
        for (int nj = 0; nj < 8; ++nj) {
          float v = sat(accs[mi][nj][r] * 0.125f, 1.0e4f);
          const int col = k0 + nj * 16 + l16;
          v = (col > grow) ? -1.0e6f : v;
          vals[nj] = v;
          mx = fmaxf(mx, v);
        }
#pragma unroll
        for (int d = 1; d < 16; d <<= 1) mx = fmaxf(mx, __shfl_xor(mx, d, 64));
        const float mnew = fmaxf(m_run[mi][r], mx);
        const float alpha = __expf(m_run[mi][r] - mnew);  // exp(-inf - finite) = 0
        float lsum = 0.f;
#pragma unroll
        for (int nj = 0; nj < 8; ++nj) {
          const float p = __expf(vals[nj] - mnew);
          lsum += p;
          accs[mi][nj][r] = p;
        }
#pragma unroll
        for (int d = 1; d < 16; d <<= 1) lsum += __shfl_xor(lsum, d, 64);
        l_run[mi][r] = alpha * l_run[mi][r] + lsum;
        m_run[mi][r] = mnew;
#pragma unroll
        for (int njo = 0; njo < 4; ++njo) acc_o[mi][njo][r] *= alpha;
      }
    }

    // O += P V  (P bounced via wave-private LDS: C-layout -> A-layout)
#pragma unroll
    for (int ks2 = 0; ks2 < 4; ++ks2) {
#pragma unroll
      for (int mi = 0; mi < 2; ++mi)
#pragma unroll
        for (int jj = 0; jj < 2; ++jj) {
          const int nj = ks2 * 2 + jj;
#pragma unroll
          for (int r = 0; r < 4; ++r)
            lsPw[(mi * 16 + quad * 4 + r) * 48 + jj * 16 + l16] = f2bf(accs[mi][nj][r]);
        }
      bf16x8 pf[2], vf[4];
#pragma unroll
      for (int mi = 0; mi < 2; ++mi)
        pf[mi] = *(const bf16x8*)&lsPw[(mi * 16 + l16) * 48 + quad * 8];
#pragma unroll
      for (int njo = 0; njo < 4; ++njo)
        vf[njo] = *(const bf16x8*)&lsV[sw_off<16>(njo * 16 + l16, ks2 * 4 + quad)];
#pragma unroll
      for (int mi = 0; mi < 2; ++mi)
#pragma unroll
        for (int njo = 0; njo < 4; ++njo)
          acc_o[mi][njo] = MFMA_BF16(pf[mi], vf[njo], acc_o[mi][njo]);
    }
  }

#pragma unroll
  for (int mi = 0; mi < 2; ++mi)
#pragma unroll
    for (int r = 0; r < 4; ++r) {
      const int q = q0 + wm + mi * 16 + quad * 4 + r;
      const float inv = 1.0f / l_run[mi][r];  // l_run >= 1 by construction
#pragma unroll
      for (int njo = 0; njo < 4; ++njo)
        A2b[(size_t)q * 64 + njo * 16 + l16] = f2bf(sat(acc_o[mi][njo][r] * inv, 448.f));
    }
}

// ---------------- launcher ----------------
extern "C" void kernel_launch(void* const* d_in, const int* in_sizes, int n_in,
                              void* d_out, int out_size, void* d_ws, size_t ws_size,
                              hipStream_t stream) {
  (void)in_sizes; (void)n_in; (void)out_size;
  const float* x  = (const float*)d_in[0];
  const float* Wq = (const float*)d_in[1];
  const float* Wk = (const float*)d_in[2];
  const float* Wv = (const float*)d_in[3];
  const float* Wo = (const float*)d_in[4];
  const float* bo = (const float*)d_in[5];
  float* out = (float*)d_out;  // FP32 output
  char* ws = (char*)d_ws;
  const size_t MB = 1024 * 1024;
  const size_t KB = 1024;

  // scratch need = 2MB + hs*2.375MB; ws_size is call-invariant -> graph-safe
  int hs = 2;
  if      (ws_size >= 2 * MB + 16 * 2432 * KB) hs = 16;  // 40MB
  else if (ws_size >= 2 * MB +  8 * 2432 * KB) hs = 8;   // 21MB
  else if (ws_size >= 2 * MB +  4 * 2432 * KB) hs = 4;   // 11.5MB
  // hs=2 needs 6.75MB; ws >= 8MB proven by round 5's structured output.

  u16* WoT   = (u16*)(ws);                                      // [1024][1024], 2MB
  u16* Ksl   = (u16*)(ws + 2 * MB);                             // [2][2048][hs64]
  u16* VTsl  = (u16*)(ws + 2 * MB + (size_t)hs *  512 * KB);    // [2*hs][64][2048]
  u16* A2sl  = (u16*)(ws + 2 * MB + (size_t)hs * 1024 * KB);    // [2*hs][2048][64]
  u16* WT3sl = (u16*)(ws + 2 * MB + (size_t)hs * 1536 * KB);    // [3*hs64][1024]
  u16* Qsl   = (u16*)(ws + 2 * MB + (size_t)hs * 1920 * KB);    // [2][2048][hs64]

  transpose_cols<<<dim3(32, 32), dim3(32, 32), 0, stream>>>(Wo, Wo, Wo, WoT, 0, 1024);
  for (int h0 = 0; h0 < 16; h0 += hs) {
    transpose_cols<<<dim3(6 * hs, 32), dim3(32, 32), 0, stream>>>(Wq, Wk, Wv, WT3sl, h0, hs * 64);
    gemm_bt<3, 1><<<dim3((3 * hs) / 2, 32), 256, 0, stream>>>(
        (const void*)x, WT3sl, (void*)Qsl, Ksl, VTsl, nullptr, 4096, 3 * hs * 64, 1024, hs, h0);
    attn_fwd<<<dim3(16, 2 * hs), 256, 0, stream>>>(Qsl, Ksl, VTsl, A2sl, hs);
    gemm_bt<1, 0><<<dim3(8, 2 * hs), 256, 0, stream>>>(
        (const void*)A2sl, WoT, (void*)out, nullptr, nullptr, bo, 2 * hs * 128, 1024, 1024, hs, h0);
  }
}

// Round 7
// 242.640 us; speedup vs baseline: 1.0770x; 1.0770x over previous
//
#include <hip/hip_runtime.h>
#include <stdint.h>

// MHA forward.  Inputs FP32, output FP32.  Compute: bf16 MFMA, fp32 accumulate.
// B=2,S=2048,D=1024,H=16,HD=64.
//
// hs=16 fast path (ws >= 40MB, confirmed round 6):
//   x2b  : x fp32 -> xb bf16 (aliased into A2sl region; A2sl written only later)
//   t1   : Wo -> WoT bf16; Wq/Wk/Wv cols -> WT3sl bf16
//   k2   : xb @ WT3sl^T -> Qsl/Ksl [b][s][1024], VTsl [b*16+h][64][s]
//   k3   : flash attention, PAIRED q-tiles (x, 15-x): every block = 17 k-iters
//   k4   : A2sl @ WoT^T + bo -> fp32 out
// hs<16 fallback keeps round-6 fp32-A staging (no xb).

typedef unsigned short u16;
typedef __attribute__((ext_vector_type(8))) short bf16x8;
typedef __attribute__((ext_vector_type(4))) float f32x4;

#define MFMA_BF16(a, b, c) __builtin_amdgcn_mfma_f32_16x16x32_bf16((a), (b), (c), 0, 0, 0)

__device__ __forceinline__ u16 f2bf(float f) {  // RNE
  union { float f; unsigned int u; } x; x.f = f;
  unsigned int r = x.u + 0x7fffu + ((x.u >> 16) & 1u);
  return (u16)(r >> 16);
}
__device__ __forceinline__ float sat(float v, float lim) {
  return fminf(fmaxf(v, -lim), lim);
}
__device__ __forceinline__ bf16x8 pack8(float4 a, float4 b) {
  bf16x8 r;
  r[0] = (short)f2bf(a.x); r[1] = (short)f2bf(a.y);
  r[2] = (short)f2bf(a.z); r[3] = (short)f2bf(a.w);
  r[4] = (short)f2bf(b.x); r[5] = (short)f2bf(b.y);
  r[6] = (short)f2bf(b.z); r[7] = (short)f2bf(b.w);
  return r;
}

template <int CPR>
__device__ __forceinline__ int sw_off(int r, int c) {
  return (r * CPR + (c ^ (r & (CPR - 1)))) * 8;
}

// ---- x2b: fp32 -> bf16, 8 elems/thread ----
__global__ __launch_bounds__(256) void x_to_bf16(const float* __restrict__ x,
                                                 u16* __restrict__ xb) {
  const size_t i = ((size_t)blockIdx.x * 256 + threadIdx.x) * 8;
  const float4 a = *(const float4*)&x[i];
  const float4 b = *(const float4*)&x[i + 4];
  *(bf16x8*)&xb[i] = pack8(a, b);
}

// ---- t1: T[j][k] = bf16( Wg[k][h0*64 + (j - g*hsx64)] ) ----
__global__ void transpose_cols(const float* __restrict__ W0, const float* __restrict__ W1,
                               const float* __restrict__ W2, u16* __restrict__ T,
                               int h0, int hsx64) {
  __shared__ u16 t[32][33];
  const int j0 = blockIdx.x * 32;
  const int g = j0 / hsx64;
  const float* W = (g == 0) ? W0 : (g == 1) ? W1 : W2;
  const int wc0 = h0 * 64 + (j0 % hsx64);
  const int k0 = blockIdx.y * 32;
  t[threadIdx.y][threadIdx.x] =
      f2bf(W[(size_t)(k0 + threadIdx.y) * 1024 + wc0 + threadIdx.x]);
  __syncthreads();
  T[(size_t)(j0 + threadIdx.y) * 1024 + k0 + threadIdx.x] = t[threadIdx.x][threadIdx.y];
}

// ---- k2/k4: C = A[M][K] @ BT[N][K]^T, 128x128 tile ----
// AF32: A fp32 (pack during staging) else bf16.
// MODE 3: n<hs64 -> Qsl, <2*hs64 -> Ksl, else VTsl. MODE 1: +bias, fp32 out, row remap.
template <int MODE, int AF32>
__global__ __launch_bounds__(256, 2) void gemm_bt(
    const void* __restrict__ Av, const u16* __restrict__ BT,
    void* __restrict__ C0v, u16* __restrict__ C1, u16* __restrict__ C2,
    const float* __restrict__ bias, int M, int N, int K, int hs, int h0) {
  __shared__ __align__(16) u16 lsA[128 * 32];
  __shared__ __align__(16) u16 lsB[128 * 32];
  const int tid = threadIdx.x, lane = tid & 63, wv = tid >> 6;
  const int quad = lane >> 4, l16 = lane & 15;
  const int m0 = blockIdx.y * 128, n0 = blockIdx.x * 128;
  const int wm = (wv >> 1) * 64, wn = (wv & 1) * 64;
  const int hs64 = hs * 64;
  f32x4 acc[4][4] = {};

  for (int k0 = 0; k0 < K; k0 += 32) {
    bf16x8 va[2], vb[2];
#pragma unroll
    for (int c = 0; c < 2; ++c) {
      const int P = c * 256 + tid, r = P >> 2, cc = P & 3;
      if constexpr (AF32) {
        const float* Af = (const float*)Av;
        const float4 a0 = *(const float4*)&Af[(size_t)(m0 + r) * K + k0 + cc * 8];
        const float4 a1 = *(const float4*)&Af[(size_t)(m0 + r) * K + k0 + cc * 8 + 4];
        va[c] = pack8(a0, a1);
      } else {
        va[c] = *(const bf16x8*)&((const u16*)Av)[(size_t)(m0 + r) * K + k0 + cc * 8];
      }
      vb[c] = *(const bf16x8*)&BT[(size_t)(n0 + r) * K + k0 + cc * 8];
    }
    __syncthreads();
#pragma unroll
    for (int c = 0; c < 2; ++c) {
      const int P = c * 256 + tid, r = P >> 2, cc = P & 3;
      *(bf16x8*)&lsA[sw_off<4>(r, cc)] = va[c];
      *(bf16x8*)&lsB[sw_off<4>(r, cc)] = vb[c];
    }
    __syncthreads();
    bf16x8 af[4], bfr[4];
#pragma unroll
    for (int i = 0; i < 4; ++i) af[i] = *(const bf16x8*)&lsA[sw_off<4>(wm + i * 16 + l16, quad)];
#pragma unroll
    for (int j = 0; j < 4; ++j) bfr[j] = *(const bf16x8*)&lsB[sw_off<4>(wn + j * 16 + l16, quad)];
#pragma unroll
    for (int i = 0; i < 4; ++i)
#pragma unroll
      for (int j = 0; j < 4; ++j) acc[i][j] = MFMA_BF16(af[i], bfr[j], acc[i][j]);
  }

#pragma unroll
  for (int i = 0; i < 4; ++i)
#pragma unroll
    for (int j = 0; j < 4; ++j) {
      const int n = n0 + wn + j * 16 + l16;
      float bv = 0.f;
      if constexpr (MODE == 1) bv = bias[n];
#pragma unroll
      for (int r = 0; r < 4; ++r) {
        const int m = m0 + wm + i * 16 + quad * 4 + r;
        if constexpr (MODE == 3) {
          const float v = sat(acc[i][j][r], 448.f);
          const int b = m >> 11, s = m & 2047;
          if (n < hs64) {
            ((u16*)C0v)[((size_t)b * 2048 + s) * hs64 + n] = f2bf(v);
          } else if (n < 2 * hs64) {
            C1[((size_t)b * 2048 + s) * hs64 + (n - hs64)] = f2bf(v);
          } else {
            const int nn = n - 2 * hs64;
            C2[((size_t)(b * hs + (nn >> 6)) * 64 + (nn & 63)) * 2048 + s] = f2bf(v);
          }
        } else {
          const float v = sat(acc[i][j][r] + bv, 1024.f);
          const int b = (m >= hs * 128) ? 1 : 0;
          const int rp = m - b * hs * 128;
          ((float*)C0v)[(size_t)(b * 2048 + h0 * 128 + rp) * 1024 + n] = v;
        }
      }
    }
}

// ---- k3: causal flash attention, PAIRED q-tiles for load balance ----
// Grid (8, 2*hs): block handles q-tiles blockIdx.x and 15-blockIdx.x ->
// (x+1) + (16-x) = 17 k-iterations for every block. 256 blocks at hs=16: 1/CU.
__global__ __launch_bounds__(256, 2) void attn_fwd(
    const u16* __restrict__ Qsl, const u16* __restrict__ Ksl,
    const u16* __restrict__ VTsl, u16* __restrict__ A2sl, int hs) {
  __shared__ __align__(16) u16 lsK[128 * 64];    // 16KB [key][hd], CPR=8
  __shared__ __align__(16) u16 lsV[64 * 128];    // 16KB [hd][key], CPR=16
  __shared__ __align__(16) u16 lsP[4][32 * 48];  // per-wave P bounce
  const int tid = threadIdx.x, lane = tid & 63, wv = tid >> 6;
  const int quad = lane >> 4, l16 = lane & 15;
  const int bh = blockIdx.y;
  const int b = (bh >= hs) ? 1 : 0, hh = bh - b * hs;
  const int hs64 = hs * 64;
  const int wm = wv * 32;
  const u16* Qb = Qsl + (size_t)b * 2048 * hs64;
  const u16* Kb = Ksl + (size_t)b * 2048 * hs64;
  const u16* Vb = VTsl + (size_t)(b * hs + hh) * 64 * 2048;
  u16* A2b = A2sl + (size_t)(b * hs + hh) * 2048 * 64;
  u16* lsPw = &lsP[wv][0];

  for (int half = 0; half < 2; ++half) {
    const int qt = (half == 0) ? (int)blockIdx.x : 15 - (int)blockIdx.x;
    const int q0 = qt * 128;

    bf16x8 qf[2][2];
#pragma unroll
    for (int mi = 0; mi < 2; ++mi)
#pragma unroll
      for (int ks = 0; ks < 2; ++ks)
        qf[mi][ks] = *(const bf16x8*)&Qb[(size_t)(q0 + wm + mi * 16 + l16) * hs64 +
                                         hh * 64 + ks * 32 + quad * 8];

    float m_run[2][4], l_run[2][4];
    f32x4 acc_o[2][4] = {};
#pragma unroll
    for (int mi = 0; mi < 2; ++mi)
#pragma unroll
      for (int r = 0; r < 4; ++r) { m_run[mi][r] = -INFINITY; l_run[mi][r] = 0.f; }

    for (int kt = 0; kt <= qt; ++kt) {
      const int k0 = kt * 128;
      bf16x8 vk[4], vv[4];
#pragma unroll
      for (int c = 0; c < 4; ++c) {
        const int P = c * 256 + tid;
        vk[c] = *(const bf16x8*)&Kb[(size_t)(k0 + (P >> 3)) * hs64 + hh * 64 + (P & 7) * 8];
        vv[c] = *(const bf16x8*)&Vb[(size_t)(P >> 4) * 2048 + k0 + (P & 15) * 8];
      }
      __syncthreads();
#pragma unroll
      for (int c = 0; c < 4; ++c) {
        const int P = c * 256 + tid;
        *(bf16x8*)&lsK[sw_off<8>(P >> 3, P & 7)] = vk[c];
        *(bf16x8*)&lsV[sw_off<16>(P >> 4, P & 15)] = vv[c];
      }
      __syncthreads();

      // S = Q K^T
      f32x4 accs[2][8] = {};
#pragma unroll
      for (int ks = 0; ks < 2; ++ks) {
        bf16x8 kf[8];
#pragma unroll
        for (int nj = 0; nj < 8; ++nj)
          kf[nj] = *(const bf16x8*)&lsK[sw_off<8>(nj * 16 + l16, ks * 4 + quad)];
#pragma unroll
        for (int mi = 0; mi < 2; ++mi)
#pragma unroll
          for (int nj = 0; nj < 8; ++nj)
            accs[mi][nj] = MFMA_BF16(qf[mi][ks], kf[nj], accs[mi][nj]);
      }

      // online softmax (scale=1/8)
#pragma unroll
      for (int mi = 0; mi < 2; ++mi) {
#pragma unroll
        for (int r = 0; r < 4; ++r) {
          const int grow = q0 + wm + mi * 16 + quad * 4 + r;
          float vals[8], mx = -1.0e6f;
#pragma unroll
          for (int nj = 0; nj < 8; ++nj) {
            float v = sat(accs[mi][nj][r] * 0.125f, 1.0e4f);
            const int col = k0 + nj * 16 + l16;
            v = (col > grow) ? -1.0e6f : v;
            vals[nj] = v;
            mx = fmaxf(mx, v);
          }
#pragma unroll
          for (int d = 1; d < 16; d <<= 1) mx = fmaxf(mx, __shfl_xor(mx, d, 64));
          const float mnew = fmaxf(m_run[mi][r], mx);
          const float alpha = __expf(m_run[mi][r] - mnew);
          float lsum = 0.f;
#pragma unroll
          for (int nj = 0; nj < 8; ++nj) {
            const float p = __expf(vals[nj] - mnew);
            lsum += p;
            accs[mi][nj][r] = p;
          }
#pragma unroll
          for (int d = 1; d < 16; d <<= 1) lsum += __shfl_xor(lsum, d, 64);
          l_run[mi][r] = alpha * l_run[mi][r] + lsum;
          m_run[mi][r] = mnew;
#pragma unroll
          for (int njo = 0; njo < 4; ++njo) acc_o[mi][njo][r] *= alpha;
        }
      }

      // O += P V
#pragma unroll
      for (int ks2 = 0; ks2 < 4; ++ks2) {
#pragma unroll
        for (int mi = 0; mi < 2; ++mi)
#pragma unroll
          for (int jj = 0; jj < 2; ++jj) {
            const int nj = ks2 * 2 + jj;
#pragma unroll
            for (int r = 0; r < 4; ++r)
              lsPw[(mi * 16 + quad * 4 + r) * 48 + jj * 16 + l16] = f2bf(accs[mi][nj][r]);
          }
        bf16x8 pf[2], vf[4];
#pragma unroll
        for (int mi = 0; mi < 2; ++mi)
          pf[mi] = *(const bf16x8*)&lsPw[(mi * 16 + l16) * 48 + quad * 8];
#pragma unroll
        for (int njo = 0; njo < 4; ++njo)
          vf[njo] = *(const bf16x8*)&lsV[sw_off<16>(njo * 16 + l16, ks2 * 4 + quad)];
#pragma unroll
        for (int mi = 0; mi < 2; ++mi)
#pragma unroll
          for (int njo = 0; njo < 4; ++njo)
            acc_o[mi][njo] = MFMA_BF16(pf[mi], vf[njo], acc_o[mi][njo]);
      }
    }

#pragma unroll
    for (int mi = 0; mi < 2; ++mi)
#pragma unroll
      for (int r = 0; r < 4; ++r) {
        const int q = q0 + wm + mi * 16 + quad * 4 + r;
        const float inv = 1.0f / l_run[mi][r];
#pragma unroll
        for (int njo = 0; njo < 4; ++njo)
          A2b[(size_t)q * 64 + njo * 16 + l16] = f2bf(sat(acc_o[mi][njo][r] * inv, 448.f));
      }
    __syncthreads();  // half 0's LDS reads done before half 1 restages
  }
}

// ---------------- launcher ----------------
extern "C" void kernel_launch(void* const* d_in, const int* in_sizes, int n_in,
                              void* d_out, int out_size, void* d_ws, size_t ws_size,
                              hipStream_t stream) {
  (void)in_sizes; (void)n_in; (void)out_size;
  const float* x  = (const float*)d_in[0];
  const float* Wq = (const float*)d_in[1];
  const float* Wk = (const float*)d_in[2];
  const float* Wv = (const float*)d_in[3];
  const float* Wo = (const float*)d_in[4];
  const float* bo = (const float*)d_in[5];
  float* out = (float*)d_out;
  char* ws = (char*)d_ws;
  const size_t MB = 1024 * 1024;
  const size_t KB = 1024;

  int hs = 2;
  if      (ws_size >= 2 * MB + 16 * 2432 * KB) hs = 16;  // 40MB (confirmed available)
  else if (ws_size >= 2 * MB +  8 * 2432 * KB) hs = 8;
  else if (ws_size >= 2 * MB +  4 * 2432 * KB) hs = 4;

  u16* WoT   = (u16*)(ws);
  u16* Ksl   = (u16*)(ws + 2 * MB);
  u16* VTsl  = (u16*)(ws + 2 * MB + (size_t)hs *  512 * KB);
  u16* A2sl  = (u16*)(ws + 2 * MB + (size_t)hs * 1024 * KB);  // hs*512KB
  u16* WT3sl = (u16*)(ws + 2 * MB + (size_t)hs * 1536 * KB);
  u16* Qsl   = (u16*)(ws + 2 * MB + (size_t)hs * 1920 * KB);

  transpose_cols<<<dim3(32, 32), dim3(32, 32), 0, stream>>>(Wo, Wo, Wo, WoT, 0, 1024);
  if (hs == 16) {
    // xb aliases A2sl (exactly 8MB at hs=16): xb consumed by k2, A2sl written by k3 later.
    u16* xb = A2sl;
    x_to_bf16<<<2048, 256, 0, stream>>>(x, xb);
    transpose_cols<<<dim3(96, 32), dim3(32, 32), 0, stream>>>(Wq, Wk, Wv, WT3sl, 0, 1024);
    gemm_bt<3, 0><<<dim3(24, 32), 256, 0, stream>>>(
        (const void*)xb, WT3sl, (void*)Qsl, Ksl, VTsl, nullptr, 4096, 3072, 1024, 16, 0);
    attn_fwd<<<dim3(8, 32), 256, 0, stream>>>(Qsl, Ksl, VTsl, A2sl, 16);
    gemm_bt<1, 0><<<dim3(8, 32), 256, 0, stream>>>(
        (const void*)A2sl, WoT, (void*)out, nullptr, nullptr, bo, 4096, 1024, 1024, 16, 0);
  } else {
    for (int h0 = 0; h0 < 16; h0 += hs) {
      transpose_cols<<<dim3(6 * hs, 32), dim3(32, 32), 0, stream>>>(Wq, Wk, Wv, WT3sl, h0, hs * 64);
      gemm_bt<3, 1><<<dim3((3 * hs) / 2, 32), 256, 0, stream>>>(
          (const void*)x, WT3sl, (void*)Qsl, Ksl, VTsl, nullptr, 4096, 3 * hs * 64, 1024, hs, h0);
      attn_fwd<<<dim3(8, 2 * hs), 256, 0, stream>>>(Qsl, Ksl, VTsl, A2sl, hs);
      gemm_bt<1, 0><<<dim3(8, 2 * hs), 256, 0, stream>>>(
          (const void*)A2sl, WoT, (void*)out, nullptr, nullptr, bo, 2 * hs * 128, 1024, 1024, hs, h0);
    }
  }
}

// Round 8
// 228.046 us; speedup vs baseline: 1.1459x; 1.0640x over previous
//
#include <hip/hip_runtime.h>
#include <stdint.h>

// MHA forward.  Inputs FP32, output FP32.  Compute: bf16 MFMA, fp32 accumulate.
// B=2,S=2048,D=1024,H=16,HD=64.
//
// hs=16 fast path (ws >= 40MB, confirmed):
//   x2b  : x fp32 -> xb bf16 (aliased into A2sl region)
//   t1   : Wo -> WoT bf16; Wq/Wk/Wv cols -> WT3sl bf16
//   k2   : xb @ WT3sl^T -> Qsl (PRE-SCALED by 0.125*log2e) / Ksl, VTsl
//   k3   : flash attention v3: 512 thr (8 waves x 16 q-rows), paired q-tiles
//          (x, 15-x) = 17 k-iters/block, double-buffered K/V LDS + reg prefetch
//          (1 barrier/iter, load latency hidden), exp2-domain online softmax,
//          diagonal-only masking, lsP stride 40 (bank-conflict-free quads).
//   k4   : A2sl @ WoT^T + bo -> fp32 out

typedef unsigned short u16;
typedef __attribute__((ext_vector_type(8))) short bf16x8;
typedef __attribute__((ext_vector_type(4))) float f32x4;

#define MFMA_BF16(a, b, c) __builtin_amdgcn_mfma_f32_16x16x32_bf16((a), (b), (c), 0, 0, 0)

// 0.125 (1/sqrt(64)) * log2(e): folds score scale + exp->exp2 into Q epilogue
#define QSCALE 0.18033688011112042f

__device__ __forceinline__ u16 f2bf(float f) {  // RNE
  union { float f; unsigned int u; } x; x.f = f;
  unsigned int r = x.u + 0x7fffu + ((x.u >> 16) & 1u);
  return (u16)(r >> 16);
}
__device__ __forceinline__ bf16x8 pack8(float4 a, float4 b) {
  bf16x8 r;
  r[0] = (short)f2bf(a.x); r[1] = (short)f2bf(a.y);
  r[2] = (short)f2bf(a.z); r[3] = (short)f2bf(a.w);
  r[4] = (short)f2bf(b.x); r[5] = (short)f2bf(b.y);
  r[6] = (short)f2bf(b.z); r[7] = (short)f2bf(b.w);
  return r;
}

template <int CPR>
__device__ __forceinline__ int sw_off(int r, int c) {
  return (r * CPR + (c ^ (r & (CPR - 1)))) * 8;
}

// ---- x2b: fp32 -> bf16, 8 elems/thread ----
__global__ __launch_bounds__(256) void x_to_bf16(const float* __restrict__ x,
                                                 u16* __restrict__ xb) {
  const size_t i = ((size_t)blockIdx.x * 256 + threadIdx.x) * 8;
  const float4 a = *(const float4*)&x[i];
  const float4 b = *(const float4*)&x[i + 4];
  *(bf16x8*)&xb[i] = pack8(a, b);
}

// ---- t1: T[j][k] = bf16( Wg[k][h0*64 + (j - g*hsx64)] ) ----
__global__ void transpose_cols(const float* __restrict__ W0, const float* __restrict__ W1,
                               const float* __restrict__ W2, u16* __restrict__ T,
                               int h0, int hsx64) {
  __shared__ u16 t[32][33];
  const int j0 = blockIdx.x * 32;
  const int g = j0 / hsx64;
  const float* W = (g == 0) ? W0 : (g == 1) ? W1 : W2;
  const int wc0 = h0 * 64 + (j0 % hsx64);
  const int k0 = blockIdx.y * 32;
  t[threadIdx.y][threadIdx.x] =
      f2bf(W[(size_t)(k0 + threadIdx.y) * 1024 + wc0 + threadIdx.x]);
  __syncthreads();
  T[(size_t)(j0 + threadIdx.y) * 1024 + k0 + threadIdx.x] = t[threadIdx.x][threadIdx.y];
}

// ---- k2/k4: C = A[M][K] @ BT[N][K]^T, 128x128 tile ----
template <int MODE, int AF32>
__global__ __launch_bounds__(256, 2) void gemm_bt(
    const void* __restrict__ Av, const u16* __restrict__ BT,
    void* __restrict__ C0v, u16* __restrict__ C1, u16* __restrict__ C2,
    const float* __restrict__ bias, int M, int N, int K, int hs, int h0) {
  __shared__ __align__(16) u16 lsA[128 * 32];
  __shared__ __align__(16) u16 lsB[128 * 32];
  const int tid = threadIdx.x, lane = tid & 63, wv = tid >> 6;
  const int quad = lane >> 4, l16 = lane & 15;
  const int m0 = blockIdx.y * 128, n0 = blockIdx.x * 128;
  const int wm = (wv >> 1) * 64, wn = (wv & 1) * 64;
  const int hs64 = hs * 64;
  f32x4 acc[4][4] = {};

  for (int k0 = 0; k0 < K; k0 += 32) {
    bf16x8 va[2], vb[2];
#pragma unroll
    for (int c = 0; c < 2; ++c) {
      const int P = c * 256 + tid, r = P >> 2, cc = P & 3;
      if constexpr (AF32) {
        const float* Af = (const float*)Av;
        const float4 a0 = *(const float4*)&Af[(size_t)(m0 + r) * K + k0 + cc * 8];
        const float4 a1 = *(const float4*)&Af[(size_t)(m0 + r) * K + k0 + cc * 8 + 4];
        va[c] = pack8(a0, a1);
      } else {
        va[c] = *(const bf16x8*)&((const u16*)Av)[(size_t)(m0 + r) * K + k0 + cc * 8];
      }
      vb[c] = *(const bf16x8*)&BT[(size_t)(n0 + r) * K + k0 + cc * 8];
    }
    __syncthreads();
#pragma unroll
    for (int c = 0; c < 2; ++c) {
      const int P = c * 256 + tid, r = P >> 2, cc = P & 3;
      *(bf16x8*)&lsA[sw_off<4>(r, cc)] = va[c];
      *(bf16x8*)&lsB[sw_off<4>(r, cc)] = vb[c];
    }
    __syncthreads();
    bf16x8 af[4], bfr[4];
#pragma unroll
    for (int i = 0; i < 4; ++i) af[i] = *(const bf16x8*)&lsA[sw_off<4>(wm + i * 16 + l16, quad)];
#pragma unroll
    for (int j = 0; j < 4; ++j) bfr[j] = *(const bf16x8*)&lsB[sw_off<4>(wn + j * 16 + l16, quad)];
#pragma unroll
    for (int i = 0; i < 4; ++i)
#pragma unroll
      for (int j = 0; j < 4; ++j) acc[i][j] = MFMA_BF16(af[i], bfr[j], acc[i][j]);
  }

#pragma unroll
  for (int i = 0; i < 4; ++i)
#pragma unroll
    for (int j = 0; j < 4; ++j) {
      const int n = n0 + wn + j * 16 + l16;
      float bv = 0.f;
      if constexpr (MODE == 1) bv = bias[n];
#pragma unroll
      for (int r = 0; r < 4; ++r) {
        const int m = m0 + wm + i * 16 + quad * 4 + r;
        if constexpr (MODE == 3) {
          const int b = m >> 11, s = m & 2047;
          if (n < hs64) {
            // Q: pre-scale (fp32, before rounding) for exp2-domain softmax
            ((u16*)C0v)[((size_t)b * 2048 + s) * hs64 + n] = f2bf(acc[i][j][r] * QSCALE);
          } else if (n < 2 * hs64) {
            C1[((size_t)b * 2048 + s) * hs64 + (n - hs64)] = f2bf(acc[i][j][r]);
          } else {
            const int nn = n - 2 * hs64;
            C2[((size_t)(b * hs + (nn >> 6)) * 64 + (nn & 63)) * 2048 + s] =
                f2bf(acc[i][j][r]);
          }
        } else {
          const int b = (m >= hs * 128) ? 1 : 0;
          const int rp = m - b * hs * 128;
          ((float*)C0v)[(size_t)(b * 2048 + h0 * 128 + rp) * 1024 + n] =
              acc[i][j][r] + bv;
        }
      }
    }
}

// ---- k3: causal flash attention v3 ----
// Grid (8, 2*hs), 512 threads. Block pairs q-tiles (x, 15-x): 17 k-iters.
// Wave wv owns q-rows [q0 + wv*16, +16). Double-buffered K/V staging.
__global__ __launch_bounds__(512, 2) void attn_fwd(
    const u16* __restrict__ Qsl, const u16* __restrict__ Ksl,
    const u16* __restrict__ VTsl, u16* __restrict__ A2sl, int hs) {
  __shared__ __align__(16) u16 lsK[2][128 * 64];  // 2 x 16KB [key][hd], CPR=8
  __shared__ __align__(16) u16 lsV[2][64 * 128];  // 2 x 16KB [hd][key], CPR=16
  __shared__ __align__(16) u16 lsP[8][16 * 40];   // per-wave P bounce, stride 40
  const int tid = threadIdx.x, lane = tid & 63, wv = tid >> 6;
  const int quad = lane >> 4, l16 = lane & 15;
  const int bh = blockIdx.y;
  const int b = (bh >= hs) ? 1 : 0, hh = bh - b * hs;
  const int hs64 = hs * 64;
  const int wm = wv * 16;
  const u16* Qb = Qsl + (size_t)b * 2048 * hs64;
  const u16* Kb = Ksl + (size_t)b * 2048 * hs64;
  const u16* Vb = VTsl + (size_t)(b * hs + hh) * 64 * 2048;
  u16* A2b = A2sl + (size_t)(b * hs + hh) * 2048 * 64;
  u16* lsPw = &lsP[wv][0];

  const int P0 = tid, P1 = 512 + tid;  // 2 x 16B staging chunks per thread per tile

  for (int half = 0; half < 2; ++half) {
    const int qt = (half == 0) ? (int)blockIdx.x : 15 - (int)blockIdx.x;
    const int q0 = qt * 128;

    bf16x8 qf[2];
#pragma unroll
    for (int ks = 0; ks < 2; ++ks)
      qf[ks] = *(const bf16x8*)&Qb[(size_t)(q0 + wm + l16) * hs64 + hh * 64 +
                                   ks * 32 + quad * 8];

    float m_run[4], l_run[4];
    f32x4 acc_o[4] = {};
#pragma unroll
    for (int r = 0; r < 4; ++r) { m_run[r] = -INFINITY; l_run[r] = 0.f; }

    // preload tile 0
    bf16x8 vk0, vk1, vv0, vv1, nk0, nk1, nv0, nv1;
    vk0 = *(const bf16x8*)&Kb[(size_t)(P0 >> 3) * hs64 + hh * 64 + (P0 & 7) * 8];
    vk1 = *(const bf16x8*)&Kb[(size_t)(P1 >> 3) * hs64 + hh * 64 + (P1 & 7) * 8];
    vv0 = *(const bf16x8*)&Vb[(size_t)(P0 >> 4) * 2048 + (P0 & 15) * 8];
    vv1 = *(const bf16x8*)&Vb[(size_t)(P1 >> 4) * 2048 + (P1 & 15) * 8];

    for (int kt = 0; kt <= qt; ++kt) {
      const int k0 = kt * 128;
      const int buf = kt & 1;
      // write staged tile (vmcnt wait for these regs lands here, one compute later)
      *(bf16x8*)&lsK[buf][sw_off<8>(P0 >> 3, P0 & 7)] = vk0;
      *(bf16x8*)&lsK[buf][sw_off<8>(P1 >> 3, P1 & 7)] = vk1;
      *(bf16x8*)&lsV[buf][sw_off<16>(P0 >> 4, P0 & 15)] = vv0;
      *(bf16x8*)&lsV[buf][sw_off<16>(P1 >> 4, P1 & 15)] = vv1;
      // prefetch tile kt+1 (latency hidden behind this iter's compute)
      if (kt < qt) {
        const int k1 = k0 + 128;
        nk0 = *(const bf16x8*)&Kb[(size_t)(k1 + (P0 >> 3)) * hs64 + hh * 64 + (P0 & 7) * 8];
        nk1 = *(const bf16x8*)&Kb[(size_t)(k1 + (P1 >> 3)) * hs64 + hh * 64 + (P1 & 7) * 8];
        nv0 = *(const bf16x8*)&Vb[(size_t)(P0 >> 4) * 2048 + k1 + (P0 & 15) * 8];
        nv1 = *(const bf16x8*)&Vb[(size_t)(P1 >> 4) * 2048 + k1 + (P1 & 15) * 8];
      }
      __syncthreads();

      // S = Q K^T (log2-scaled by Q epilogue)
      f32x4 accs[8] = {};
#pragma unroll
      for (int ks = 0; ks < 2; ++ks)
#pragma unroll
        for (int nj = 0; nj < 8; ++nj) {
          const bf16x8 kf =
              *(const bf16x8*)&lsK[buf][sw_off<8>(nj * 16 + l16, ks * 4 + quad)];
          accs[nj] = MFMA_BF16(qf[ks], kf, accs[nj]);
        }

      // online softmax in exp2 domain; only the diagonal tile needs masking
      const bool diag = (kt == qt);
#pragma unroll
      for (int r = 0; r < 4; ++r) {
        const int grow = q0 + wm + quad * 4 + r;
        float vals[8], mx = -1.0e30f;
#pragma unroll
        for (int nj = 0; nj < 8; ++nj) {
          float v = accs[nj][r];
          if (diag) {
            const int col = k0 + nj * 16 + l16;
            v = (col > grow) ? -1.0e30f : v;
          }
          vals[nj] = v;
          mx = fmaxf(mx, v);
        }
#pragma unroll
        for (int d = 1; d < 16; d <<= 1) mx = fmaxf(mx, __shfl_xor(mx, d, 64));
        const float mnew = fmaxf(m_run[r], mx);
        const float alpha = exp2f(m_run[r] - mnew);  // exp2(-inf)=0 on first tile
        float lsum = 0.f;
#pragma unroll
        for (int nj = 0; nj < 8; ++nj) {
          const float p = exp2f(vals[nj] - mnew);
          lsum += p;
          accs[nj][r] = p;
        }
#pragma unroll
        for (int d = 1; d < 16; d <<= 1) lsum += __shfl_xor(lsum, d, 64);
        l_run[r] = alpha * l_run[r] + lsum;
        m_run[r] = mnew;
#pragma unroll
        for (int njo = 0; njo < 4; ++njo) acc_o[njo][r] *= alpha;
      }

      // O += P V  (P bounce: C-layout -> A-layout, 32 keys/step, stride 40)
#pragma unroll
      for (int ks2 = 0; ks2 < 4; ++ks2) {
#pragma unroll
        for (int jj = 0; jj < 2; ++jj)
#pragma unroll
          for (int r = 0; r < 4; ++r)
            lsPw[(quad * 4 + r) * 40 + jj * 16 + l16] = f2bf(accs[ks2 * 2 + jj][r]);
        const bf16x8 pf = *(const bf16x8*)&lsPw[l16 * 40 + quad * 8];
#pragma unroll
        for (int njo = 0; njo < 4; ++njo) {
          const bf16x8 vf =
              *(const bf16x8*)&lsV[buf][sw_off<16>(njo * 16 + l16, ks2 * 4 + quad)];
          acc_o[njo] = MFMA_BF16(pf, vf, acc_o[njo]);
        }
      }

      vk0 = nk0; vk1 = nk1; vv0 = nv0; vv1 = nv1;
    }

#pragma unroll
    for (int r = 0; r < 4; ++r) {
      const int q = q0 + wm + quad * 4 + r;
      const float inv = 1.0f / l_run[r];
#pragma unroll
      for (int njo = 0; njo < 4; ++njo)
        A2b[(size_t)q * 64 + njo * 16 + l16] = f2bf(acc_o[njo][r] * inv);
    }
    __syncthreads();  // half 0's buffers fully consumed before half 1 restages
  }
}

// ---------------- launcher ----------------
extern "C" void kernel_launch(void* const* d_in, const int* in_sizes, int n_in,
                              void* d_out, int out_size, void* d_ws, size_t ws_size,
                              hipStream_t stream) {
  (void)in_sizes; (void)n_in; (void)out_size;
  const float* x  = (const float*)d_in[0];
  const float* Wq = (const float*)d_in[1];
  const float* Wk = (const float*)d_in[2];
  const float* Wv = (const float*)d_in[3];
  const float* Wo = (const float*)d_in[4];
  const float* bo = (const float*)d_in[5];
  float* out = (float*)d_out;
  char* ws = (char*)d_ws;
  const size_t MB = 1024 * 1024;
  const size_t KB = 1024;

  int hs = 2;
  if      (ws_size >= 2 * MB + 16 * 2432 * KB) hs = 16;  // 40MB (confirmed available)
  else if (ws_size >= 2 * MB +  8 * 2432 * KB) hs = 8;
  else if (ws_size >= 2 * MB +  4 * 2432 * KB) hs = 4;

  u16* WoT   = (u16*)(ws);
  u16* Ksl   = (u16*)(ws + 2 * MB);
  u16* VTsl  = (u16*)(ws + 2 * MB + (size_t)hs *  512 * KB);
  u16* A2sl  = (u16*)(ws + 2 * MB + (size_t)hs * 1024 * KB);
  u16* WT3sl = (u16*)(ws + 2 * MB + (size_t)hs * 1536 * KB);
  u16* Qsl   = (u16*)(ws + 2 * MB + (size_t)hs * 1920 * KB);

  transpose_cols<<<dim3(32, 32), dim3(32, 32), 0, stream>>>(Wo, Wo, Wo, WoT, 0, 1024);
  if (hs == 16) {
    u16* xb = A2sl;  // aliases A2sl: consumed by k2, overwritten by k3
    x_to_bf16<<<2048, 256, 0, stream>>>(x, xb);
    transpose_cols<<<dim3(96, 32), dim3(32, 32), 0, stream>>>(Wq, Wk, Wv, WT3sl, 0, 1024);
    gemm_bt<3, 0><<<dim3(24, 32), 256, 0, stream>>>(
        (const void*)xb, WT3sl, (void*)Qsl, Ksl, VTsl, nullptr, 4096, 3072, 1024, 16, 0);
    attn_fwd<<<dim3(8, 32), 512, 0, stream>>>(Qsl, Ksl, VTsl, A2sl, 16);
    gemm_bt<1, 0><<<dim3(8, 32), 256, 0, stream>>>(
        (const void*)A2sl, WoT, (void*)out, nullptr, nullptr, bo, 4096, 1024, 1024, 16, 0);
  } else {
    for (int h0 = 0; h0 < 16; h0 += hs) {
      transpose_cols<<<dim3(6 * hs, 32), dim3(32, 32), 0, stream>>>(Wq, Wk, Wv, WT3sl, h0, hs * 64);
      gemm_bt<3, 1><<<dim3((3 * hs) / 2, 32), 256, 0, stream>>>(
          (const void*)x, WT3sl, (void*)Qsl, Ksl, VTsl, nullptr, 4096, 3 * hs * 64, 1024, hs, h0);
      attn_fwd<<<dim3(8, 2 * hs), 512, 0, stream>>>(Qsl, Ksl, VTsl, A2sl, hs);
      gemm_bt<1, 0><<<dim3(8, 2 * hs), 256, 0, stream>>>(
          (const void*)A2sl, WoT, (void*)out, nullptr, nullptr, bo, 2 * hs * 128, 1024, 1024, hs, h0);
    }
  }
}